// Round 9
// baseline (183.982 us; speedup 1.0000x reference)
//
#include <hip/hip_runtime.h>
#include <hip/hip_bf16.h>

// Problem constants
constexpr int B  = 2;
constexpr int S  = 2048;
constexpr int E  = 1024;
constexpr int H  = 16;
constexpr int DK = 64;
constexpr int M  = B * S;            // 4096 rows of x
constexpr int N3 = 3 * E;            // stacked [Wk; Wv; Wq]
constexpr long RSZ = (long)B * H * S * DK;  // one output region (4.19M elems)

using bf16x8 = __attribute__((ext_vector_type(8))) __bf16;
using bf16x4 = __attribute__((ext_vector_type(4))) __bf16;
using f32x4  = __attribute__((ext_vector_type(4))) float;

// async global->LDS, 16B/lane; LDS base wave-uniform, lane i lands at +i*16 B.
__device__ __forceinline__ void async16(__bf16* lds, const __bf16* g) {
    __builtin_amdgcn_global_load_lds(
        (const __attribute__((address_space(1))) void*)g,
        (__attribute__((address_space(3))) void*)lds, 16, 0, 0);
}

// ---------------- cvt: x and stacked W's -> bf16 ----------------
__global__ __launch_bounds__(256)
void cvt_kernel(const float* __restrict__ x, const float* __restrict__ Wk,
                const float* __restrict__ Wv, const float* __restrict__ Wq,
                __bf16* __restrict__ xb, __bf16* __restrict__ wall) {
    const long e = ((long)blockIdx.x * 256 + threadIdx.x) * 4;
    const float* src;
    __bf16* dst;
    if (e < (long)M * E) { src = x + e; dst = xb + e; }
    else {
        const long e2 = e - (long)M * E;
        const int which = (int)(e2 >> 20);
        const long off  = e2 & ((1L << 20) - 1);
        src = (which == 0 ? Wk : which == 1 ? Wv : Wq) + off;
        dst = wall + e2;
    }
    float4 f = *reinterpret_cast<const float4*>(src);
    bf16x4 o;
    o[0] = (__bf16)f.x; o[1] = (__bf16)f.y; o[2] = (__bf16)f.z; o[3] = (__bf16)f.w;
    *reinterpret_cast<bf16x4*>(dst) = o;
}

// ---------------- fused QKV GEMM v3: distance-2 pipeline ----------------
// Triple-buffered BK=32 tiles; per iter: s_waitcnt vmcnt(4) (waits ONLY tile
// i's 4 DMA loads — tiles i+1/i+2 stay in flight, AITER-style), raw s_barrier
// (each wave verified its own DMA before the barrier -> cross-wave RAW safe),
// then issue tile i+2 into the buffer freed at iter i-1 (WAR: readers passed
// the barrier). No __syncthreads in the K-loop -> no vmcnt(0) drain per iter.
__global__ __launch_bounds__(256, 3)
void qkv_gemm(const __bf16* __restrict__ xb, const __bf16* __restrict__ wall,
              const float* __restrict__ theta, __bf16* __restrict__ kvq) {
    __shared__ __align__(1024) __bf16 smem[6 * 128 * 32];   // A0|A1|A2|B0|B1|B2 = 48 KB
    __bf16* tile = smem;                                    // epilogue alias: 128x128

    const int t    = threadIdx.x;
    const int lane = t & 63;
    const int w    = t >> 6;
    const int quad = lane >> 4;
    const int l16  = lane & 15;
    const int wm   = w >> 1, wn = w & 1;      // 2x2 wave grid, 64x64 each
    const int mbase = blockIdx.y * 128;
    const int nbase = blockIdx.x * 128;

    f32x4 acc[4][4];
    #pragma unroll
    for (int i = 0; i < 4; i++)
        #pragma unroll
        for (int j = 0; j < 4; j++)
            acc[i][j] = f32x4{0.f, 0.f, 0.f, 0.f};

    const int srow = lane >> 2;
    const int srcc = (lane & 3) ^ ((lane >> 3) & 3);
    const __bf16* ga = xb   + (long)(mbase + srow) * E + srcc * 8;
    const __bf16* gb = wall + (long)(nbase + srow) * E + srcc * 8;

    const int csw = (l16 >> 1) & 3;

    // prologue: tiles 0 and 1 into buffers 0 and 1 (8 loads outstanding)
    #pragma unroll
    for (int pt = 0; pt < 2; pt++) {
        #pragma unroll
        for (int c = 0; c < 2; c++) {
            async16(smem + pt * 4096 +         (c * 64 + w * 16) * 32,
                    ga + (long)(c * 64 + w * 16) * E + pt * 32);
            async16(smem + pt * 4096 + 12288 + (c * 64 + w * 16) * 32,
                    gb + (long)(c * 64 + w * 16) * E + pt * 32);
        }
    }

    int cur = 0;
    constexpr int ITERS = E / 32;   // 32
    for (int it = 0; it < ITERS; it++) {
        // wait own tile-it loads (oldest 4); keep the rest in flight
        if (it < ITERS - 1) asm volatile("s_waitcnt vmcnt(4)" ::: "memory");
        else                asm volatile("s_waitcnt vmcnt(0)" ::: "memory");
        asm volatile("s_barrier" ::: "memory");   // raw: no drain

        if (it + 2 < ITERS) {
            const int pb  = (cur == 0) ? 2 : cur - 1;   // buffer freed at iter it-1
            const int kk2 = (it + 2) * 32;
            #pragma unroll
            for (int c = 0; c < 2; c++) {
                async16(smem + pb * 4096 +         (c * 64 + w * 16) * 32,
                        ga + (long)(c * 64 + w * 16) * E + kk2);
                async16(smem + pb * 4096 + 12288 + (c * 64 + w * 16) * 32,
                        gb + (long)(c * 64 + w * 16) * E + kk2);
            }
        }

        const __bf16* Asb = smem + cur * 4096;
        const __bf16* Bsb = smem + cur * 4096 + 12288;
        bf16x8 a[4], b[4];
        #pragma unroll
        for (int i = 0; i < 4; i++)
            a[i] = *reinterpret_cast<const bf16x8*>(
                &Asb[(wm * 64 + i * 16 + l16) * 32 + (quad ^ csw) * 8]);
        #pragma unroll
        for (int j = 0; j < 4; j++)
            b[j] = *reinterpret_cast<const bf16x8*>(
                &Bsb[(wn * 64 + j * 16 + l16) * 32 + (quad ^ csw) * 8]);
        #pragma unroll
        for (int i = 0; i < 4; i++)
            #pragma unroll
            for (int j = 0; j < 4; j++)
                acc[i][j] = __builtin_amdgcn_mfma_f32_16x16x32_bf16(a[i], b[j], acc[i][j], 0, 0, 0);

        cur = (cur == 2) ? 0 : cur + 1;
    }

    const int region = nbase >> 10;           // block-uniform 0=K 1=V 2=Q
    const int bb = mbase >> 11;
    if (region == 1) {
        __syncthreads();                      // full drain before aliasing smem
        #pragma unroll
        for (int i = 0; i < 4; i++) {
            const int cchunk = wm * 8 + i * 2 + (quad >> 1);
            #pragma unroll
            for (int j = 0; j < 4; j++) {
                const int cirb = wn * 64 + j * 16 + l16;
                const int cs = cchunk ^ l16;
                bf16x4 pk;
                #pragma unroll
                for (int r = 0; r < 4; r++) pk[r] = (__bf16)acc[i][j][r];
                *reinterpret_cast<bf16x4*>(&tile[cirb * 128 + cs * 8 + (quad & 1) * 4]) = pk;
            }
        }
        __syncthreads();
        const int h0 = (nbase & 1023) >> 6;
        __bf16* vt = kvq + RSZ;               // V^T region: [B,H,DK,S]
        #pragma unroll
        for (int p = 0; p < 8; p++) {
            const int dcol = p * 16 + (t >> 4);
            const int lc = t & 15;
            const int cs2 = lc ^ (dcol & 15);
            bf16x8 vv = *reinterpret_cast<const bf16x8*>(&tile[dcol * 128 + cs2 * 8]);
            const int hh = h0 + (dcol >> 6), d = dcol & 63;
            *reinterpret_cast<bf16x8*>(
                &vt[((long)(bb * H + hh) * DK + d) * S + (mbase & 2047) + lc * 8]) = vv;
        }
    } else {
        __bf16* dst = kvq + (region == 2 ? 2 * RSZ : 0);
        float th[4];
        if (region == 2) {
            #pragma unroll
            for (int j = 0; j < 4; j++) th[j] = theta[j * 16 + l16];
        }
        #pragma unroll
        for (int i = 0; i < 4; i++) {
            const int row0 = mbase + wm * 64 + i * 16 + quad * 4;
            #pragma unroll
            for (int j = 0; j < 4; j++) {
                const int cir = (nbase & 1023) + wn * 64 + j * 16 + l16;
                const int h = cir >> 6, d = cir & 63;
                #pragma unroll
                for (int r = 0; r < 4; r++) {
                    const int s = (row0 + r) & 2047;
                    float v = acc[i][j][r];
                    if (region == 2) v = cosf(v + th[j]) * 0.125f;  // fold 1/sqrt(DK)
                    dst[((long)(bb * H + h) * S + s) * DK + d] = (__bf16)v;
                }
            }
        }
    }
}

// ---------------- attention v9: S^T + distance-2 pipeline ----------------
// R8's S^T formulation (verified) with triple-buffered K/V tiles and the same
// vmcnt(N)/raw-barrier ordering: wait own tile-i DMA (2 loads) BEFORE the
// barrier, issue tile i+2 after it, never drain to 0 mid-loop.
__global__ __launch_bounds__(256, 2)
void attn_kernel(const __bf16* __restrict__ q_ws, const __bf16* __restrict__ k_ws,
                 const __bf16* __restrict__ v_ws, float* __restrict__ out) {
    __shared__ __align__(1024) __bf16 Ks[3][32 * 64];   // [key][d] swizzled, 4 KB each
    __shared__ __align__(1024) __bf16 Vs[3][64 * 32];   // [d][key] swizzled, 4 KB each
    __shared__ __align__(16)   __bf16 Pl[4][32 * 40];   // per-wave P [qrow][key], stride 40
    __shared__ __align__(16)   float  ls_lds[4][32];

    const int lane = threadIdx.x & 63;
    const int w    = threadIdx.x >> 6;          // 0..3
    const int quad = lane >> 4;
    const int l16  = lane & 15;

    // XCD swizzle: 4 bh per id%8 class -> per-XCD K/V set 2MB < 4MB L2 (R6-verified)
    const int id    = blockIdx.x;
    const int bh    = (id & 7) + 8 * ((id >> 3) & 3);
    const int qbase = (id >> 5) * 128 + w * 32;  // wave owns 32 q-rows

    const __bf16* qp = q_ws + (long)bh * S * DK;
    const __bf16* kp = k_ws + (long)bh * S * DK;
    const __bf16* vp = v_ws + (long)bh * DK * S;   // [DK][S]

    // staging decompositions (one async16 per wave per buffer)
    const int ksr = lane >> 3, ksc = (lane & 7) ^ (lane >> 3);          // K: key-off, src chunk
    const int vsr = lane >> 2, vsc = (lane & 3) ^ ((lane >> 2) & 3);    // V: d-off, src chunk

    // Q B-frags resident: B[k=d=ks*32+quad*8+j][n=qrow=nt*16+l16]
    bf16x8 bq[2][2];
    #pragma unroll
    for (int nt = 0; nt < 2; nt++)
        #pragma unroll
        for (int ks = 0; ks < 2; ks++)
            bq[nt][ks] = *reinterpret_cast<const bf16x8*>(
                qp + (long)(qbase + nt * 16 + l16) * DK + ks * 32 + quad * 8);

    f32x4 o[2][4];     // O[qrow-tile mt][d-tile nt]
    #pragma unroll
    for (int i = 0; i < 2; i++)
        #pragma unroll
        for (int j = 0; j < 4; j++) o[i][j] = f32x4{0.f, 0.f, 0.f, 0.f};
    float lsum[2] = {0.f, 0.f};   // per-lane partial row sums, qrow = nt*16+l16

    // prologue: tiles 0 and 1 into buffers 0 and 1 (order K,V,K,V -> FIFO)
    #pragma unroll
    for (int pt = 0; pt < 2; pt++) {
        async16(&Ks[pt][(w * 8) * 64],  kp + (long)(pt * 32 + w * 8 + ksr) * DK + ksc * 8);
        async16(&Vs[pt][(w * 16) * 32], vp + (long)(w * 16 + vsr) * S + pt * 32 + vsc * 8);
    }

    int cur = 0;
    constexpr int ITERS = S / 32;   // 64
    for (int it = 0; it < ITERS; it++) {
        if (it < ITERS - 1) asm volatile("s_waitcnt vmcnt(2)" ::: "memory");
        else                asm volatile("s_waitcnt vmcnt(0)" ::: "memory");
        asm volatile("s_barrier" ::: "memory");   // raw: no drain

        if (it + 2 < ITERS) {
            const int pb  = (cur == 0) ? 2 : cur - 1;
            const int kt2 = (it + 2) * 32;
            async16(&Ks[pb][(w * 8) * 64],
                    kp + (long)(kt2 + w * 8 + ksr) * DK + ksc * 8);
            async16(&Vs[pb][(w * 16) * 32],
                    vp + (long)(w * 16 + vsr) * S + kt2 + vsc * 8);
        }

        // ---- S^T = K Q^T : A=K[m=key][k=d], B=Q^T -> C[key(regs)][qrow(lanes)] ----
        f32x4 sacc[2][2];  // [key-tile mt][qrow-tile nt]
        #pragma unroll
        for (int i = 0; i < 2; i++)
            #pragma unroll
            for (int j = 0; j < 2; j++) sacc[i][j] = f32x4{0.f, 0.f, 0.f, 0.f};
        #pragma unroll
        for (int ks = 0; ks < 2; ks++) {
            bf16x8 ak[2];
            #pragma unroll
            for (int mt = 0; mt < 2; mt++)
                ak[mt] = *reinterpret_cast<const bf16x8*>(
                    &Ks[cur][(mt * 16 + l16) * 64 + ((ks * 4 + quad) ^ (l16 & 7)) * 8]);
            #pragma unroll
            for (int mt = 0; mt < 2; mt++)
                #pragma unroll
                for (int nt = 0; nt < 2; nt++)
                    sacc[mt][nt] = __builtin_amdgcn_mfma_f32_16x16x32_bf16(
                        ak[mt], bq[nt][ks], sacc[mt][nt], 0, 0, 0);
        }

        // ---- P = exp(S^T): pack 4 consecutive keys (regs) -> one b64 store ----
        #pragma unroll
        for (int mt = 0; mt < 2; mt++)
            #pragma unroll
            for (int nt = 0; nt < 2; nt++) {
                float p0 = __expf(sacc[mt][nt][0]);
                float p1 = __expf(sacc[mt][nt][1]);
                float p2 = __expf(sacc[mt][nt][2]);
                float p3 = __expf(sacc[mt][nt][3]);
                lsum[nt] += (p0 + p1) + (p2 + p3);
                bf16x4 pk;
                pk[0] = (__bf16)p0; pk[1] = (__bf16)p1;
                pk[2] = (__bf16)p2; pk[3] = (__bf16)p3;
                *reinterpret_cast<bf16x4*>(
                    &Pl[w][(nt * 16 + l16) * 40 + mt * 16 + quad * 4]) = pk;
            }

        // ---- O += P V : A=P[m=qrow][k=key(32)], B=V[k=key][n=d] ----
        #pragma unroll
        for (int mt = 0; mt < 2; mt++) {
            bf16x8 ap = *reinterpret_cast<const bf16x8*>(
                &Pl[w][(mt * 16 + l16) * 40 + quad * 8]);
            #pragma unroll
            for (int nt = 0; nt < 4; nt++) {
                bf16x8 bv = *reinterpret_cast<const bf16x8*>(
                    &Vs[cur][(nt * 16 + l16) * 32 + (quad ^ (l16 & 3)) * 8]);
                o[mt][nt] = __builtin_amdgcn_mfma_f32_16x16x32_bf16(ap, bv, o[mt][nt], 0, 0, 0);
            }
        }

        cur = (cur == 2) ? 0 : cur + 1;
    }

    // ---- finalize l: reduce partials across the 4 quads, broadcast via LDS ----
    #pragma unroll
    for (int nt = 0; nt < 2; nt++) {
        float v = lsum[nt];
        v += __shfl_xor(v, 16);
        v += __shfl_xor(v, 32);
        ls_lds[w][nt * 16 + l16] = v;   // quads duplicate-write same value (benign)
    }

    // ---- epilogue: out[b][s][h*64+d] = O / l ----
    const int b = bh >> 4, h = bh & 15;
    #pragma unroll
    for (int mt = 0; mt < 2; mt++) {
        f32x4 lv = *reinterpret_cast<const f32x4*>(&ls_lds[w][mt * 16 + quad * 4]);
        #pragma unroll
        for (int r = 0; r < 4; r++) {
            const float inv = 1.0f / lv[r];
            const int srow = qbase + mt * 16 + quad * 4 + r;
            #pragma unroll
            for (int nt = 0; nt < 4; nt++)
                out[(long)(b * S + srow) * E + h * DK + nt * 16 + l16] = o[mt][nt][r] * inv;
        }
    }
}

// -------- fallback proj (direct fp32 loads, used only if ws too small) --------
__device__ inline bf16x8 cvt_frag(const float* __restrict__ p) {
    float4 f0 = *reinterpret_cast<const float4*>(p);
    float4 f1 = *reinterpret_cast<const float4*>(p + 4);
    bf16x8 r;
    r[0] = (__bf16)f0.x; r[1] = (__bf16)f0.y; r[2] = (__bf16)f0.z; r[3] = (__bf16)f0.w;
    r[4] = (__bf16)f1.x; r[5] = (__bf16)f1.y; r[6] = (__bf16)f1.z; r[7] = (__bf16)f1.w;
    return r;
}
template <int MODE>
__global__ __launch_bounds__(256, 2)
void proj_kernel(const float* __restrict__ x, const float* __restrict__ W,
                 const float* __restrict__ theta, __bf16* __restrict__ out) {
    const int lane = threadIdx.x & 63;
    const int w    = threadIdx.x >> 6;
    const int quad = lane >> 4;
    const int l16  = lane & 15;
    const int mbase = blockIdx.y * 128 + w * 32;
    const int nbase = blockIdx.x * 128;
    f32x4 acc[2][8];
    #pragma unroll
    for (int i = 0; i < 2; i++)
        #pragma unroll
        for (int j = 0; j < 8; j++) acc[i][j] = f32x4{0.f, 0.f, 0.f, 0.f};
    float th[4];
    if (MODE == 2) {
        #pragma unroll
        for (int j = 0; j < 4; j++) th[j] = theta[j * 16 + l16];
    }
    for (int kk = 0; kk < E; kk += 32) {
        bf16x8 a[2], b[8];
        #pragma unroll
        for (int mt = 0; mt < 2; mt++)
            a[mt] = cvt_frag(x + (long)(mbase + mt * 16 + l16) * E + kk + quad * 8);
        #pragma unroll
        for (int nt = 0; nt < 8; nt++)
            b[nt] = cvt_frag(W + (long)(nbase + nt * 16 + l16) * E + kk + quad * 8);
        #pragma unroll
        for (int mt = 0; mt < 2; mt++)
            #pragma unroll
            for (int nt = 0; nt < 8; nt++)
                acc[mt][nt] = __builtin_amdgcn_mfma_f32_16x16x32_bf16(a[mt], b[nt], acc[mt][nt], 0, 0, 0);
    }
    #pragma unroll
    for (int mt = 0; mt < 2; mt++) {
        const int row0 = mbase + mt * 16 + quad * 4;
        #pragma unroll
        for (int nt = 0; nt < 8; nt++) {
            const int col = nbase + nt * 16 + l16;
            const int h = col >> 6, d = col & 63;
            #pragma unroll
            for (int r = 0; r < 4; r++) {
                const int row = row0 + r;
                const int bb = row >> 11, s = row & 2047;
                float v = acc[mt][nt][r];
                if (MODE == 2) v = cosf(v + th[nt & 3]) * 0.125f;
                long idx;
                if (MODE == 1) idx = ((long)(bb * H + h) * DK + d) * S + s;
                else           idx = ((long)(bb * H + h) * S + s) * DK + d;
                out[idx] = (__bf16)v;
            }
        }
    }
}

extern "C" void kernel_launch(void* const* d_in, const int* in_sizes, int n_in,
                              void* d_out, int out_size, void* d_ws, size_t ws_size,
                              hipStream_t stream) {
    const float* x     = (const float*)d_in[0];
    const float* Wk    = (const float*)d_in[1];
    const float* Wv    = (const float*)d_in[2];
    const float* Wq    = (const float*)d_in[3];
    const float* theta = (const float*)d_in[4];
    float* out = (float*)d_out;

    // ws: kvq[3*RSZ: K | V^T | Q] | xb[M*E] | wall[N3*E]
    __bf16* kvq  = (__bf16*)d_ws;
    __bf16* xb   = kvq + 3 * RSZ;
    __bf16* wall = xb + (long)M * E;
    __bf16* k_ws = kvq;
    __bf16* v_t  = kvq + RSZ;
    __bf16* q_ws = kvq + 2 * RSZ;

    const size_t need = (3 * RSZ + (long)M * E + (long)N3 * E) * 2;
    dim3 blk(256);
    if (ws_size >= need) {
        cvt_kernel<<<dim3(7168), blk, 0, stream>>>(x, Wk, Wv, Wq, xb, wall);
        qkv_gemm<<<dim3(N3 / 128, M / 128), blk, 0, stream>>>(xb, wall, theta, kvq);
    } else {
        dim3 gp(E / 128, M / 128);
        proj_kernel<0><<<gp, blk, 0, stream>>>(x, Wk, nullptr, k_ws);
        proj_kernel<1><<<gp, blk, 0, stream>>>(x, Wv, nullptr, v_t);
        proj_kernel<2><<<gp, blk, 0, stream>>>(x, Wq, theta, q_ws);
    }

    attn_kernel<<<dim3(512), blk, 0, stream>>>(q_ws, k_ws, v_t, out);
}

// Round 10
// 171.643 us; speedup vs baseline: 1.0719x; 1.0719x over previous
//
#include <hip/hip_runtime.h>
#include <hip/hip_bf16.h>

// Problem constants
constexpr int B  = 2;
constexpr int S  = 2048;
constexpr int E  = 1024;
constexpr int H  = 16;
constexpr int DK = 64;
constexpr int M  = B * S;            // 4096 rows of x
constexpr int N3 = 3 * E;            // stacked [Wk; Wv; Wq]
constexpr long RSZ = (long)B * H * S * DK;  // one output region (4.19M elems)

// Q scale: 1/sqrt(DK) * log2(e) -> softmax via raw v_exp_f32 (base-2), no mul.
#define QSCALE 0.18033688011112042f

using bf16x8 = __attribute__((ext_vector_type(8))) __bf16;
using bf16x4 = __attribute__((ext_vector_type(4))) __bf16;
using f32x4  = __attribute__((ext_vector_type(4))) float;

// async global->LDS, 16B/lane; LDS base wave-uniform, lane i lands at +i*16 B.
__device__ __forceinline__ void async16(__bf16* lds, const __bf16* g) {
    __builtin_amdgcn_global_load_lds(
        (const __attribute__((address_space(1))) void*)g,
        (__attribute__((address_space(3))) void*)lds, 16, 0, 0);
}

// ---------------- cvt: x and stacked W's -> bf16 ----------------
__global__ __launch_bounds__(256)
void cvt_kernel(const float* __restrict__ x, const float* __restrict__ Wk,
                const float* __restrict__ Wv, const float* __restrict__ Wq,
                __bf16* __restrict__ xb, __bf16* __restrict__ wall) {
    const long e = ((long)blockIdx.x * 256 + threadIdx.x) * 4;
    const float* src;
    __bf16* dst;
    if (e < (long)M * E) { src = x + e; dst = xb + e; }
    else {
        const long e2 = e - (long)M * E;
        const int which = (int)(e2 >> 20);
        const long off  = e2 & ((1L << 20) - 1);
        src = (which == 0 ? Wk : which == 1 ? Wv : Wq) + off;
        dst = wall + e2;
    }
    float4 f = *reinterpret_cast<const float4*>(src);
    bf16x4 o;
    o[0] = (__bf16)f.x; o[1] = (__bf16)f.y; o[2] = (__bf16)f.z; o[3] = (__bf16)f.w;
    *reinterpret_cast<bf16x4*>(dst) = o;
}

// ---------------- fused QKV GEMM v3: distance-2 pipeline (R9-verified) ----------------
__global__ __launch_bounds__(256, 3)
void qkv_gemm(const __bf16* __restrict__ xb, const __bf16* __restrict__ wall,
              const float* __restrict__ theta, __bf16* __restrict__ kvq) {
    __shared__ __align__(1024) __bf16 smem[6 * 128 * 32];   // A0|A1|A2|B0|B1|B2 = 48 KB
    __bf16* tile = smem;                                    // epilogue alias: 128x128

    const int t    = threadIdx.x;
    const int lane = t & 63;
    const int w    = t >> 6;
    const int quad = lane >> 4;
    const int l16  = lane & 15;
    const int wm   = w >> 1, wn = w & 1;      // 2x2 wave grid, 64x64 each
    const int mbase = blockIdx.y * 128;
    const int nbase = blockIdx.x * 128;

    f32x4 acc[4][4];
    #pragma unroll
    for (int i = 0; i < 4; i++)
        #pragma unroll
        for (int j = 0; j < 4; j++)
            acc[i][j] = f32x4{0.f, 0.f, 0.f, 0.f};

    const int srow = lane >> 2;
    const int srcc = (lane & 3) ^ ((lane >> 3) & 3);
    const __bf16* ga = xb   + (long)(mbase + srow) * E + srcc * 8;
    const __bf16* gb = wall + (long)(nbase + srow) * E + srcc * 8;

    const int csw = (l16 >> 1) & 3;

    // prologue: tiles 0 and 1 into buffers 0 and 1 (8 loads outstanding)
    #pragma unroll
    for (int pt = 0; pt < 2; pt++) {
        #pragma unroll
        for (int c = 0; c < 2; c++) {
            async16(smem + pt * 4096 +         (c * 64 + w * 16) * 32,
                    ga + (long)(c * 64 + w * 16) * E + pt * 32);
            async16(smem + pt * 4096 + 12288 + (c * 64 + w * 16) * 32,
                    gb + (long)(c * 64 + w * 16) * E + pt * 32);
        }
    }

    int cur = 0;
    constexpr int ITERS = E / 32;   // 32
    for (int it = 0; it < ITERS; it++) {
        if (it < ITERS - 1) asm volatile("s_waitcnt vmcnt(4)" ::: "memory");
        else                asm volatile("s_waitcnt vmcnt(0)" ::: "memory");
        asm volatile("s_barrier" ::: "memory");   // raw: no drain

        if (it + 2 < ITERS) {
            const int pb  = (cur == 0) ? 2 : cur - 1;
            const int kk2 = (it + 2) * 32;
            #pragma unroll
            for (int c = 0; c < 2; c++) {
                async16(smem + pb * 4096 +         (c * 64 + w * 16) * 32,
                        ga + (long)(c * 64 + w * 16) * E + kk2);
                async16(smem + pb * 4096 + 12288 + (c * 64 + w * 16) * 32,
                        gb + (long)(c * 64 + w * 16) * E + kk2);
            }
        }

        const __bf16* Asb = smem + cur * 4096;
        const __bf16* Bsb = smem + cur * 4096 + 12288;
        bf16x8 a[4], b[4];
        #pragma unroll
        for (int i = 0; i < 4; i++)
            a[i] = *reinterpret_cast<const bf16x8*>(
                &Asb[(wm * 64 + i * 16 + l16) * 32 + (quad ^ csw) * 8]);
        #pragma unroll
        for (int j = 0; j < 4; j++)
            b[j] = *reinterpret_cast<const bf16x8*>(
                &Bsb[(wn * 64 + j * 16 + l16) * 32 + (quad ^ csw) * 8]);
        #pragma unroll
        for (int i = 0; i < 4; i++)
            #pragma unroll
            for (int j = 0; j < 4; j++)
                acc[i][j] = __builtin_amdgcn_mfma_f32_16x16x32_bf16(a[i], b[j], acc[i][j], 0, 0, 0);

        cur = (cur == 2) ? 0 : cur + 1;
    }

    const int region = nbase >> 10;           // block-uniform 0=K 1=V 2=Q
    const int bb = mbase >> 11;
    if (region == 1) {
        __syncthreads();                      // full drain before aliasing smem
        #pragma unroll
        for (int i = 0; i < 4; i++) {
            const int cchunk = wm * 8 + i * 2 + (quad >> 1);
            #pragma unroll
            for (int j = 0; j < 4; j++) {
                const int cirb = wn * 64 + j * 16 + l16;
                const int cs = cchunk ^ l16;
                bf16x4 pk;
                #pragma unroll
                for (int r = 0; r < 4; r++) pk[r] = (__bf16)acc[i][j][r];
                *reinterpret_cast<bf16x4*>(&tile[cirb * 128 + cs * 8 + (quad & 1) * 4]) = pk;
            }
        }
        __syncthreads();
        const int h0 = (nbase & 1023) >> 6;
        __bf16* vt = kvq + RSZ;               // V^T region: [B,H,DK,S]
        #pragma unroll
        for (int p = 0; p < 8; p++) {
            const int dcol = p * 16 + (t >> 4);
            const int lc = t & 15;
            const int cs2 = lc ^ (dcol & 15);
            bf16x8 vv = *reinterpret_cast<const bf16x8*>(&tile[dcol * 128 + cs2 * 8]);
            const int hh = h0 + (dcol >> 6), d = dcol & 63;
            *reinterpret_cast<bf16x8*>(
                &vt[((long)(bb * H + hh) * DK + d) * S + (mbase & 2047) + lc * 8]) = vv;
        }
    } else {
        __bf16* dst = kvq + (region == 2 ? 2 * RSZ : 0);
        float th[4];
        if (region == 2) {
            #pragma unroll
            for (int j = 0; j < 4; j++) th[j] = theta[j * 16 + l16];
        }
        #pragma unroll
        for (int i = 0; i < 4; i++) {
            const int row0 = mbase + wm * 64 + i * 16 + quad * 4;
            #pragma unroll
            for (int j = 0; j < 4; j++) {
                const int cir = (nbase & 1023) + wn * 64 + j * 16 + l16;
                const int h = cir >> 6, d = cir & 63;
                #pragma unroll
                for (int r = 0; r < 4; r++) {
                    const int s = (row0 + r) & 2047;
                    float v = acc[i][j][r];
                    if (region == 2) v = cosf(v + th[j]) * QSCALE;  // fold 1/sqrt(DK)*log2e
                    dst[((long)(bb * H + h) * S + s) * DK + d] = (__bf16)v;
                }
            }
        }
    }
}

// ---------------- attention v10: S^T + KT=64 + distance-2 ----------------
// R9's S^T formulation with 64-key tiles: half the barrier crossings, 2x work
// per chain segment (the R9 stall was 2 half-idle chains/SIMD convoying on
// per-iter barriers). Triple-buffered 8 KB K/V tiles; P via stride-72 LDS
// (b64 stores 2-way=free; b128 reads at the 1KB/wave structural floor).
// exp2-domain softmax (log2e folded into Q scale) -> raw v_exp_f32.
__global__ __launch_bounds__(256, 2)
void attn_kernel(const __bf16* __restrict__ q_ws, const __bf16* __restrict__ k_ws,
                 const __bf16* __restrict__ v_ws, float* __restrict__ out) {
    __shared__ __align__(1024) __bf16 Ks[3][64 * 64];   // [key][d] swizzled, 8 KB each
    __shared__ __align__(1024) __bf16 Vs[3][64 * 64];   // [d][key] swizzled, 8 KB each
    __shared__ __align__(16)   __bf16 Pl[4][32 * 72];   // per-wave P [qrow][key], stride 72
    __shared__ __align__(16)   float  ls_lds[4][32];

    const int lane = threadIdx.x & 63;
    const int w    = threadIdx.x >> 6;          // 0..3
    const int quad = lane >> 4;
    const int l16  = lane & 15;

    // XCD swizzle: 4 bh per id%8 class -> per-XCD K/V set 2MB < 4MB L2 (R6-verified)
    const int id    = blockIdx.x;
    const int bh    = (id & 7) + 8 * ((id >> 3) & 3);
    const int qbase = (id >> 5) * 128 + w * 32;  // wave owns 32 q-rows

    const __bf16* qp = q_ws + (long)bh * S * DK;
    const __bf16* kp = k_ws + (long)bh * S * DK;
    const __bf16* vp = v_ws + (long)bh * DK * S;   // [DK][S]

    // staging: 8 rows x 8 chunks(16B) per async16; source chunk XOR-swizzled
    const int sr  = lane >> 3;
    const int scs = (lane & 7) ^ sr;

    // Q B-frags resident: B[k=d=ks*32+quad*8+j][n=qrow=nt*16+l16]
    bf16x8 bq[2][2];
    #pragma unroll
    for (int nt = 0; nt < 2; nt++)
        #pragma unroll
        for (int ks = 0; ks < 2; ks++)
            bq[nt][ks] = *reinterpret_cast<const bf16x8*>(
                qp + (long)(qbase + nt * 16 + l16) * DK + ks * 32 + quad * 8);

    f32x4 o[2][4];     // O[qrow-tile mt][d-tile nt]
    #pragma unroll
    for (int i = 0; i < 2; i++)
        #pragma unroll
        for (int j = 0; j < 4; j++) o[i][j] = f32x4{0.f, 0.f, 0.f, 0.f};
    float lsum[2] = {0.f, 0.f};   // per-lane partial row sums, qrow = nt*16+l16

    // prologue: tiles 0,1 into buffers 0,1 — 4 DMA issues per tile per wave
    #pragma unroll
    for (int pt = 0; pt < 2; pt++) {
        #pragma unroll
        for (int i = 0; i < 2; i++) {
            const int row = w * 16 + i * 8;
            async16(&Ks[pt][row * 64], kp + (long)(pt * 64 + row + sr) * DK + scs * 8);
            async16(&Vs[pt][row * 64], vp + (long)(row + sr) * S + pt * 64 + scs * 8);
        }
    }

    int cur = 0;
    constexpr int ITERS = S / 64;   // 32
    for (int it = 0; it < ITERS; it++) {
        if (it < ITERS - 1) asm volatile("s_waitcnt vmcnt(4)" ::: "memory");
        else                asm volatile("s_waitcnt vmcnt(0)" ::: "memory");
        asm volatile("s_barrier" ::: "memory");   // raw: no drain

        if (it + 2 < ITERS) {
            const int kt2 = (it + 2) * 64;
            const int pb  = (cur == 0) ? 2 : cur - 1;
            #pragma unroll
            for (int i = 0; i < 2; i++) {
                const int row = w * 16 + i * 8;
                async16(&Ks[pb][row * 64], kp + (long)(kt2 + row + sr) * DK + scs * 8);
                async16(&Vs[pb][row * 64], vp + (long)(row + sr) * S + kt2 + scs * 8);
            }
        }

        // ---- S^T = K Q^T : C[key(regs) 64][qrow(lanes) 32] ----
        f32x4 sacc[4][2];  // [key-tile mt][qrow-tile nt]
        #pragma unroll
        for (int i = 0; i < 4; i++)
            #pragma unroll
            for (int j = 0; j < 2; j++) sacc[i][j] = f32x4{0.f, 0.f, 0.f, 0.f};
        #pragma unroll
        for (int ks = 0; ks < 2; ks++) {
            bf16x8 ak[4];
            #pragma unroll
            for (int mt = 0; mt < 4; mt++)
                ak[mt] = *reinterpret_cast<const bf16x8*>(
                    &Ks[cur][(mt * 16 + l16) * 64 + ((ks * 4 + quad) ^ (l16 & 7)) * 8]);
            #pragma unroll
            for (int mt = 0; mt < 4; mt++)
                #pragma unroll
                for (int nt = 0; nt < 2; nt++)
                    sacc[mt][nt] = __builtin_amdgcn_mfma_f32_16x16x32_bf16(
                        ak[mt], bq[nt][ks], sacc[mt][nt], 0, 0, 0);
        }

        // ---- P = exp2(S^T): 4 consecutive keys (regs) -> one b64 store ----
        #pragma unroll
        for (int mt = 0; mt < 4; mt++)
            #pragma unroll
            for (int nt = 0; nt < 2; nt++) {
                float p0 = __builtin_amdgcn_exp2f(sacc[mt][nt][0]);
                float p1 = __builtin_amdgcn_exp2f(sacc[mt][nt][1]);
                float p2 = __builtin_amdgcn_exp2f(sacc[mt][nt][2]);
                float p3 = __builtin_amdgcn_exp2f(sacc[mt][nt][3]);
                lsum[nt] += (p0 + p1) + (p2 + p3);
                bf16x4 pk;
                pk[0] = (__bf16)p0; pk[1] = (__bf16)p1;
                pk[2] = (__bf16)p2; pk[3] = (__bf16)p3;
                *reinterpret_cast<bf16x4*>(
                    &Pl[w][(nt * 16 + l16) * 72 + mt * 16 + quad * 4]) = pk;
            }

        // ---- O += P V : A=P[m=qrow][k=key], B=V[k=key][n=d], 2 k-halves ----
        #pragma unroll
        for (int kh = 0; kh < 2; kh++) {
            bf16x8 bv[4];
            #pragma unroll
            for (int nt = 0; nt < 4; nt++)
                bv[nt] = *reinterpret_cast<const bf16x8*>(
                    &Vs[cur][(nt * 16 + l16) * 64 + ((kh * 4 + quad) ^ (l16 & 7)) * 8]);
            #pragma unroll
            for (int mt = 0; mt < 2; mt++) {
                bf16x8 ap = *reinterpret_cast<const bf16x8*>(
                    &Pl[w][(mt * 16 + l16) * 72 + kh * 32 + quad * 8]);
                #pragma unroll
                for (int nt = 0; nt < 4; nt++)
                    o[mt][nt] = __builtin_amdgcn_mfma_f32_16x16x32_bf16(
                        ap, bv[nt], o[mt][nt], 0, 0, 0);
            }
        }

        cur = (cur == 2) ? 0 : cur + 1;
    }

    // ---- finalize l: reduce partials across the 4 quads, broadcast via LDS ----
    #pragma unroll
    for (int nt = 0; nt < 2; nt++) {
        float v = lsum[nt];
        v += __shfl_xor(v, 16);
        v += __shfl_xor(v, 32);
        ls_lds[w][nt * 16 + l16] = v;   // quads duplicate-write same value (benign)
    }

    // ---- epilogue: out[b][s][h*64+d] = O / l ----
    const int b = bh >> 4, h = bh & 15;
    #pragma unroll
    for (int mt = 0; mt < 2; mt++) {
        f32x4 lv = *reinterpret_cast<const f32x4*>(&ls_lds[w][mt * 16 + quad * 4]);
        #pragma unroll
        for (int r = 0; r < 4; r++) {
            const float inv = 1.0f / lv[r];
            const int srow = qbase + mt * 16 + quad * 4 + r;
            #pragma unroll
            for (int nt = 0; nt < 4; nt++)
                out[(long)(b * S + srow) * E + h * DK + nt * 16 + l16] = o[mt][nt][r] * inv;
        }
    }
}

// -------- fallback proj (direct fp32 loads, used only if ws too small) --------
__device__ inline bf16x8 cvt_frag(const float* __restrict__ p) {
    float4 f0 = *reinterpret_cast<const float4*>(p);
    float4 f1 = *reinterpret_cast<const float4*>(p + 4);
    bf16x8 r;
    r[0] = (__bf16)f0.x; r[1] = (__bf16)f0.y; r[2] = (__bf16)f0.z; r[3] = (__bf16)f0.w;
    r[4] = (__bf16)f1.x; r[5] = (__bf16)f1.y; r[6] = (__bf16)f1.z; r[7] = (__bf16)f1.w;
    return r;
}
template <int MODE>
__global__ __launch_bounds__(256, 2)
void proj_kernel(const float* __restrict__ x, const float* __restrict__ W,
                 const float* __restrict__ theta, __bf16* __restrict__ out) {
    const int lane = threadIdx.x & 63;
    const int w    = threadIdx.x >> 6;
    const int quad = lane >> 4;
    const int l16  = lane & 15;
    const int mbase = blockIdx.y * 128 + w * 32;
    const int nbase = blockIdx.x * 128;
    f32x4 acc[2][8];
    #pragma unroll
    for (int i = 0; i < 2; i++)
        #pragma unroll
        for (int j = 0; j < 8; j++) acc[i][j] = f32x4{0.f, 0.f, 0.f, 0.f};
    float th[4];
    if (MODE == 2) {
        #pragma unroll
        for (int j = 0; j < 4; j++) th[j] = theta[j * 16 + l16];
    }
    for (int kk = 0; kk < E; kk += 32) {
        bf16x8 a[2], b[8];
        #pragma unroll
        for (int mt = 0; mt < 2; mt++)
            a[mt] = cvt_frag(x + (long)(mbase + mt * 16 + l16) * E + kk + quad * 8);
        #pragma unroll
        for (int nt = 0; nt < 8; nt++)
            b[nt] = cvt_frag(W + (long)(nbase + nt * 16 + l16) * E + kk + quad * 8);
        #pragma unroll
        for (int mt = 0; mt < 2; mt++)
            #pragma unroll
            for (int nt = 0; nt < 8; nt++)
                acc[mt][nt] = __builtin_amdgcn_mfma_f32_16x16x32_bf16(a[mt], b[nt], acc[mt][nt], 0, 0, 0);
    }
    #pragma unroll
    for (int mt = 0; mt < 2; mt++) {
        const int row0 = mbase + mt * 16 + quad * 4;
        #pragma unroll
        for (int nt = 0; nt < 8; nt++) {
            const int col = nbase + nt * 16 + l16;
            const int h = col >> 6, d = col & 63;
            #pragma unroll
            for (int r = 0; r < 4; r++) {
                const int row = row0 + r;
                const int bb = row >> 11, s = row & 2047;
                float v = acc[mt][nt][r];
                if (MODE == 2) v = cosf(v + th[nt & 3]) * QSCALE;
                long idx;
                if (MODE == 1) idx = ((long)(bb * H + h) * DK + d) * S + s;
                else           idx = ((long)(bb * H + h) * S + s) * DK + d;
                out[idx] = (__bf16)v;
            }
        }
    }
}

extern "C" void kernel_launch(void* const* d_in, const int* in_sizes, int n_in,
                              void* d_out, int out_size, void* d_ws, size_t ws_size,
                              hipStream_t stream) {
    const float* x     = (const float*)d_in[0];
    const float* Wk    = (const float*)d_in[1];
    const float* Wv    = (const float*)d_in[2];
    const float* Wq    = (const float*)d_in[3];
    const float* theta = (const float*)d_in[4];
    float* out = (float*)d_out;

    // ws: kvq[3*RSZ: K | V^T | Q] | xb[M*E] | wall[N3*E]
    __bf16* kvq  = (__bf16*)d_ws;
    __bf16* xb   = kvq + 3 * RSZ;
    __bf16* wall = xb + (long)M * E;
    __bf16* k_ws = kvq;
    __bf16* v_t  = kvq + RSZ;
    __bf16* q_ws = kvq + 2 * RSZ;

    const size_t need = (3 * RSZ + (long)M * E + (long)N3 * E) * 2;
    dim3 blk(256);
    if (ws_size >= need) {
        cvt_kernel<<<dim3(7168), blk, 0, stream>>>(x, Wk, Wv, Wq, xb, wall);
        qkv_gemm<<<dim3(N3 / 128, M / 128), blk, 0, stream>>>(xb, wall, theta, kvq);
    } else {
        dim3 gp(E / 128, M / 128);
        proj_kernel<0><<<gp, blk, 0, stream>>>(x, Wk, nullptr, k_ws);
        proj_kernel<1><<<gp, blk, 0, stream>>>(x, Wv, nullptr, v_t);
        proj_kernel<2><<<gp, blk, 0, stream>>>(x, Wq, theta, q_ws);
    }

    attn_kernel<<<dim3(512), blk, 0, stream>>>(q_ws, k_ws, v_t, out);
}